// Round 12
// baseline (382.529 us; speedup 1.0000x reference)
//
#include <hip/hip_runtime.h>
#include <stdint.h>

// R18: two contained changes targeting the measured split (attn 96.6us,
// non-attn ~244us of which gemms ~190-200us):
//  1. gemm_bt BK 32->64: halves the per-K-step vmcnt(0)+barrier drains
//     (m98: ~20% of the m97 structure). LDS 8->32KB (>=3 blocks/CU kept;
//     avoids m132's BK=128 cliff). Same staged bytes, frags gain kk dim.
//  2. attn: one block computes TWO heads of the same KV group against each
//     staged K/V tile (K/V identical across the pair): halves K/V FETCH +
//     staging + barriers per head-unit, doubles independent compute per
//     barrier window. LDS stays 32KB, VGPR ~90 uncapped, grid 1024.

typedef unsigned short u16;
typedef short bf16x8 __attribute__((ext_vector_type(8)));
typedef float f32x4 __attribute__((ext_vector_type(4)));

#define D_MODEL 2048
#define QKV_DIM 3072
#define NUM_HEADS 32
#define HEAD_DIM 64
#define SEQ 2048
#define MTOT 4096

static __device__ __forceinline__ u16 f2bf(float f){
  uint32_t u = __builtin_bit_cast(uint32_t, f);
  u += 0x7FFFu + ((u >> 16) & 1u);
  return (u16)(u >> 16);
}

static __device__ __forceinline__ float exp2_fast(float x){
  float r;
  asm("v_exp_f32 %0, %1" : "=v"(r) : "v"(x));
  return r;
}

static __device__ __forceinline__ uint32_t cvt_pk_bf16(float lo, float hi){
  uint32_t r;
  asm("v_cvt_pk_bf16_f32 %0, %1, %2" : "=v"(r) : "v"(lo), "v"(hi));
  return r;
}

static __device__ __forceinline__ void gload16(const u16* g, u16* l){
  __builtin_amdgcn_global_load_lds(
      (__attribute__((address_space(1))) uint32_t*)(uintptr_t)g,
      (__attribute__((address_space(3))) uint32_t*)l,
      16, 0, 0);
}

__global__ __launch_bounds__(256)
void cvt_bf16(const float* __restrict__ in, u16* __restrict__ out, int n,
              float scl){
  const int i = (blockIdx.x * 256 + threadIdx.x) * 8;
  if (i >= n) return;
  float4 a = *(const float4*)(in + i);
  float4 b = *(const float4*)(in + i + 4);
  union { u16 h[8]; uint4 v; } t;
  t.h[0]=f2bf(a.x*scl); t.h[1]=f2bf(a.y*scl); t.h[2]=f2bf(a.z*scl); t.h[3]=f2bf(a.w*scl);
  t.h[4]=f2bf(b.x*scl); t.h[5]=f2bf(b.y*scl); t.h[6]=f2bf(b.z*scl); t.h[7]=f2bf(b.w*scl);
  *(uint4*)(out + i) = t.v;
}

// C[M,N] = A[M,K] @ B[N,K]^T. m97 structure, BK=64 (halved barrier count).
template <bool F32OUT>
__global__ __launch_bounds__(256)
void gemm_bt(const u16* __restrict__ A, const u16* __restrict__ B,
             void* __restrict__ Cv, int M, int N, int K){
  constexpr int BK = 64;
  __shared__ __attribute__((aligned(16))) u16 As[128*BK];
  __shared__ __attribute__((aligned(16))) u16 Bs[128*BK];
  const int tid  = threadIdx.x;
  const int wave = tid >> 6, lane = tid & 63;
  const int quad = lane >> 4, l16 = lane & 15;
  const int wrow = wave >> 1, wcol = wave & 1;
  const int m0 = blockIdx.y * 128, n0 = blockIdx.x * 128;
  const int srow = lane >> 3, scol = (lane & 7) * 8;   // 8 rows x 64 cols chunks

  const f32x4 zero = {0.f, 0.f, 0.f, 0.f};
  f32x4 acc[4][4];
#pragma unroll
  for (int i = 0; i < 4; i++)
#pragma unroll
    for (int j = 0; j < 4; j++) acc[i][j] = zero;

  for (int k0 = 0; k0 < K; k0 += BK){
#pragma unroll
    for (int t = 0; t < 4; t++){
      const int c = wave*4 + t;   // chunk: rows c*8 .. c*8+7
      gload16(A + (size_t)(m0 + c*8 + srow)*K + k0 + scol, As + c*512);
      gload16(B + (size_t)(n0 + c*8 + srow)*K + k0 + scol, Bs + c*512);
    }
    __syncthreads();
    bf16x8 af[4][2], bfr[4][2];
#pragma unroll
    for (int mi = 0; mi < 4; mi++)
#pragma unroll
      for (int kk = 0; kk < 2; kk++)
        af[mi][kk] = *(const bf16x8*)(As + (wrow*64 + mi*16 + l16)*BK + kk*32 + quad*8);
#pragma unroll
    for (int ni = 0; ni < 4; ni++)
#pragma unroll
      for (int kk = 0; kk < 2; kk++)
        bfr[ni][kk] = *(const bf16x8*)(Bs + (wcol*64 + ni*16 + l16)*BK + kk*32 + quad*8);
#pragma unroll
    for (int mi = 0; mi < 4; mi++)
#pragma unroll
      for (int ni = 0; ni < 4; ni++)
#pragma unroll
        for (int kk = 0; kk < 2; kk++)
          acc[mi][ni] = __builtin_amdgcn_mfma_f32_16x16x32_bf16(af[mi][kk], bfr[ni][kk], acc[mi][ni], 0, 0, 0);
    __syncthreads();
  }
#pragma unroll
  for (int mi = 0; mi < 4; mi++)
#pragma unroll
    for (int ni = 0; ni < 4; ni++){
      const int col = n0 + wcol*64 + ni*16 + l16;
#pragma unroll
      for (int r = 0; r < 4; r++){
        const int row = m0 + wrow*64 + mi*16 + quad*4 + r;
        if constexpr (F32OUT)
          ((float*)Cv)[(size_t)row*N + col] = acc[mi][ni][r];
        else
          ((u16*)Cv)[(size_t)row*N + col] = f2bf(acc[mi][ni][r]);
      }
    }
}

// kvtrans: build per-(b,hk,j) 8KB K and V tiles in the exact (swizzled) LDS
// image attn wants. K[row=key][chunk c] stored at row*64 + (c^(row&7))*8.
// V is transposed (rows=d) with the PV k-permutation baked into the column
// order, then the same XOR swizzle.
__global__ __launch_bounds__(256)
void kvtrans(const u16* __restrict__ QKV, u16* __restrict__ Ksw,
             u16* __restrict__ Vsw){
  __shared__ u16 Ls[64*72];
  const int tid = threadIdx.x;
  const int st = blockIdx.x, hk = blockIdx.y, b = blockIdx.z;
  const size_t rb = (size_t)b * SEQ;
  const size_t tbase = ((size_t)(b*8 + hk)*32 + st) * 4096;

#pragma unroll
  for (int t = 0; t < 2; t++){
    const int task = t*256 + tid;
    const int r = task >> 3, c = task & 7;
    uint4 kv = *(const uint4*)(QKV + (rb + st*64 + r)*QKV_DIM + 2048 + hk*HEAD_DIM + c*8);
    *(uint4*)(Ksw + tbase + r*64 + (size_t)((c ^ (r & 7)) * 8)) = kv;
  }
#pragma unroll
  for (int t = 0; t < 2; t++){
    const int task = t*256 + tid;
    const int r = task >> 3, c = task & 7;
    *(uint4*)(Ls + r*72 + c*8) =
        *(const uint4*)(QKV + (rb + st*64 + r)*QKV_DIM + 2560 + hk*HEAD_DIM + c*8);
  }
  __syncthreads();
#pragma unroll
  for (int t = 0; t < 2; t++){
    const int task = t*256 + tid;
    const int d = task >> 3, sc = task & 7;
    union { u16 h[8]; uint4 v; } tmp;
#pragma unroll
    for (int e = 0; e < 8; e++){
      const int key = ((2*(sc>>2) + (e>>2))<<4) + ((sc&3)<<2) + (e&3);
      tmp.h[e] = Ls[key*72 + d];
    }
    *(uint4*)(Vsw + tbase + d*64 + (size_t)((sc ^ (d & 7)) * 8)) = tmp.v;
  }
}

// one head's QK + online-softmax (log2, defer-max) + in-register P + PV,
// against the currently staged swizzled K/V tile.
static __device__ __forceinline__ void head_step(
    const u16* __restrict__ Ksb, const u16* __restrict__ Vtb,
    const bf16x8* qf, f32x4* oacc, float& m_i, float& l_i,
    int quad, int l16, int sw, bool diag, int qrow){
  const f32x4 zero = {0.f, 0.f, 0.f, 0.f};
  f32x4 st[4];
#pragma unroll
  for (int ni = 0; ni < 4; ni++){
    f32x4 s = zero;
#pragma unroll
    for (int ss = 0; ss < 2; ss++){
      bf16x8 kf = *(const bf16x8*)(Ksb + ((ni*16 + l16) << 6) +
                                   (((ss*4 + quad) ^ sw) << 3));
      s = __builtin_amdgcn_mfma_f32_16x16x32_bf16(kf, qf[ss], s, 0, 0, 0);
    }
    st[ni] = s;
  }
  if (diag){
#pragma unroll
    for (int ni = 0; ni < 4; ni++)
#pragma unroll
      for (int r = 0; r < 4; r++)
        if (ni*16 + quad*4 + r > qrow) st[ni][r] = -INFINITY;
  }
  float mx = fmaxf(fmaxf(fmaxf(st[0][0], st[0][1]), fmaxf(st[0][2], st[0][3])),
                   fmaxf(fmaxf(st[1][0], st[1][1]), fmaxf(st[1][2], st[1][3])));
  mx = fmaxf(mx, fmaxf(fmaxf(fmaxf(st[2][0], st[2][1]), fmaxf(st[2][2], st[2][3])),
                       fmaxf(fmaxf(st[3][0], st[3][1]), fmaxf(st[3][2], st[3][3]))));
  mx = fmaxf(mx, __shfl_xor(mx, 16));
  mx = fmaxf(mx, __shfl_xor(mx, 32));

  if (__all(mx <= m_i + 10.f)){
    float ps = 0.f;
#pragma unroll
    for (int ni = 0; ni < 4; ni++)
#pragma unroll
      for (int r = 0; r < 4; r++){
        const float p = exp2_fast(st[ni][r] - m_i);
        st[ni][r] = p;
        ps += p;
      }
    ps += __shfl_xor(ps, 16);
    ps += __shfl_xor(ps, 32);
    l_i += ps;
  } else {
    const float mn = fmaxf(m_i, mx);
    const float alpha = exp2_fast(m_i - mn);
    float ps = 0.f;
#pragma unroll
    for (int ni = 0; ni < 4; ni++)
#pragma unroll
      for (int r = 0; r < 4; r++){
        const float p = exp2_fast(st[ni][r] - mn);
        st[ni][r] = p;
        ps += p;
      }
    ps += __shfl_xor(ps, 16);
    ps += __shfl_xor(ps, 32);
    l_i = l_i*alpha + ps;
    m_i = mn;
    float ar[4];
#pragma unroll
    for (int r = 0; r < 4; r++) ar[r] = __shfl(alpha, quad*4 + r);
#pragma unroll
    for (int ci = 0; ci < 4; ci++)
#pragma unroll
      for (int r = 0; r < 4; r++) oacc[ci][r] *= ar[r];
  }

  bf16x8 pfr[2];
#pragma unroll
  for (int ss = 0; ss < 2; ss++){
    union { uint32_t w[4]; bf16x8 v; } pk;
    pk.w[0] = cvt_pk_bf16(st[2*ss][0],   st[2*ss][1]);
    pk.w[1] = cvt_pk_bf16(st[2*ss][2],   st[2*ss][3]);
    pk.w[2] = cvt_pk_bf16(st[2*ss+1][0], st[2*ss+1][1]);
    pk.w[3] = cvt_pk_bf16(st[2*ss+1][2], st[2*ss+1][3]);
    pfr[ss] = pk.v;
  }
#pragma unroll
  for (int ss = 0; ss < 2; ss++)
#pragma unroll
    for (int ci = 0; ci < 4; ci++){
      bf16x8 vf = *(const bf16x8*)(Vtb + ((ci*16 + l16) << 6) +
                                   (((ss*4 + quad) ^ sw) << 3));
      oacc[ci] = __builtin_amdgcn_mfma_f32_16x16x32_bf16(pfr[ss], vf, oacc[ci], 0, 0, 0);
    }
}

// attn: TWO heads (same KV group) per block sharing staged K/V; swapped
// QK^T, in-register P, log2 softmax + defer-max, complement-balanced qt,
// double-buffered gload_lds staging, XOR-swizzled reads.
__global__ __launch_bounds__(256)
void attn(const u16* __restrict__ Q, const u16* __restrict__ Ksw,
          const u16* __restrict__ Vsw, u16* __restrict__ O, int qs){
  __shared__ __attribute__((aligned(16))) u16 Ks[2][64*64];
  __shared__ __attribute__((aligned(16))) u16 Vt[2][64*64];
  const int tid = threadIdx.x;
  const int wave = tid >> 6, lane = tid & 63, quad = lane >> 4, l16 = lane & 15;
  const int g_ = (blockIdx.x + blockIdx.y) & 31;
  const int qt = blockIdx.z ? (31 - g_) : g_;
  const int hp = blockIdx.y, b = blockIdx.z;
  const int h0 = hp*2, h1 = h0 + 1;
  const int hk = hp >> 1;                  // both heads share this KV group
  const size_t rb = (size_t)b * SEQ;
  const size_t hb = ((size_t)(b*8 + hk)) * 32;

  const int qrow = wave*16 + l16;
  const int sw = l16 & 7;

  bf16x8 qfA[2], qfB[2];
  {
    const u16* qpA = Q + (rb + qt*64 + wave*16 + l16)*qs + h0*HEAD_DIM;
    qfA[0] = *(const bf16x8*)(qpA + quad*8);
    qfA[1] = *(const bf16x8*)(qpA + 32 + quad*8);
    const u16* qpB = Q + (rb + qt*64 + wave*16 + l16)*qs + h1*HEAD_DIM;
    qfB[0] = *(const bf16x8*)(qpB + quad*8);
    qfB[1] = *(const bf16x8*)(qpB + 32 + quad*8);
  }
  const f32x4 zero = {0.f, 0.f, 0.f, 0.f};
  f32x4 oA[4], oB[4];
#pragma unroll
  for (int i = 0; i < 4; i++){ oA[i] = zero; oB[i] = zero; }
  float mA = -INFINITY, lA = 0.f, mB = -INFINITY, lB = 0.f;

  // prologue: stage tile 0 into buffer 0
  {
    const u16* kt = Ksw + hb * 4096;
    const u16* vt = Vsw + hb * 4096;
#pragma unroll
    for (int t = 0; t < 2; t++){
      const int ch = wave*2 + t;
      gload16(kt + ch*512 + lane*8, &Ks[0][ch*512]);
      gload16(vt + ch*512 + lane*8, &Vt[0][ch*512]);
    }
  }
  int cur = 0;

  for (int j = 0; j <= qt; ++j){
    __syncthreads();
    if (j < qt){
      const u16* kt = Ksw + (hb + j + 1) * 4096;
      const u16* vt = Vsw + (hb + j + 1) * 4096;
#pragma unroll
      for (int t = 0; t < 2; t++){
        const int ch = wave*2 + t;
        gload16(kt + ch*512 + lane*8, &Ks[cur^1][ch*512]);
        gload16(vt + ch*512 + lane*8, &Vt[cur^1][ch*512]);
      }
    }
    const u16* Ksb = Ks[cur];
    const u16* Vtb = Vt[cur];
    const bool diag = (j == qt);

    head_step(Ksb, Vtb, qfA, oA, mA, lA, quad, l16, sw, diag, qrow);
    head_step(Ksb, Vtb, qfB, oB, mB, lB, quad, l16, sw, diag, qrow);
    cur ^= 1;
  }

  float lfA[4], lfB[4];
#pragma unroll
  for (int r = 0; r < 4; r++){
    lfA[r] = __shfl(lA, quad*4 + r);
    lfB[r] = __shfl(lB, quad*4 + r);
  }
#pragma unroll
  for (int ci = 0; ci < 4; ci++)
#pragma unroll
    for (int r = 0; r < 4; r++){
      const size_t row = rb + qt*64 + wave*16 + quad*4 + r;
      O[row*D_MODEL + h0*HEAD_DIM + ci*16 + l16] = f2bf(oA[ci][r] / lfA[r]);
      O[row*D_MODEL + h1*HEAD_DIM + ci*16 + l16] = f2bf(oB[ci][r] / lfB[r]);
    }
}

extern "C" void kernel_launch(void* const* d_in, const int* in_sizes, int n_in,
                              void* d_out, int out_size, void* d_ws, size_t ws_size,
                              hipStream_t stream){
  const float* x  = (const float*)d_in[0];
  const float* Wq = (const float*)d_in[1];
  const float* Wk = (const float*)d_in[2];
  const float* Wv = (const float*)d_in[3];
  const float* Wo = (const float*)d_in[4];
  float* out = (float*)d_out;

  u16* xb   = (u16*)d_ws;                    // x / later attn-out  [4096,2048]
  u16* Wb   = xb + (size_t)MTOT*D_MODEL;     // fused weights [3072,2048]
  u16* QKVb = (u16*)d_out;                   // QKV scratch [4096,3072] bf16
  // swizzled K/V tiles live in Wb's Wq region: dead after gemm1, overwritten
  // by the Wo cvt AFTER attn. 2M u16 each.
  u16* Kswz = Wb;
  u16* Vswz = Wb + (size_t)2*1024*1024;

  const int nx  = MTOT*D_MODEL;
  const int nwq = D_MODEL*D_MODEL;
  const int nwk = 512*D_MODEL;
  const float QSCL = 0.125f * 1.44269504f;   // softmax scale * log2(e)

  cvt_bf16<<<nx/2048, 256, 0, stream>>>(x, xb, nx, 1.0f);
  cvt_bf16<<<nwq/2048, 256, 0, stream>>>(Wq, Wb, nwq, QSCL);
  cvt_bf16<<<nwk/2048, 256, 0, stream>>>(Wk, Wb + (size_t)D_MODEL*D_MODEL, nwk, 1.0f);
  cvt_bf16<<<nwk/2048, 256, 0, stream>>>(Wv, Wb + (size_t)2560*D_MODEL, nwk, 1.0f);
  gemm_bt<false><<<dim3(QKV_DIM/128, MTOT/128), 256, 0, stream>>>(xb, Wb, QKVb, MTOT, QKV_DIM, D_MODEL);
  kvtrans<<<dim3(SEQ/64, 8, 2), 256, 0, stream>>>(QKVb, Kswz, Vswz);
  attn<<<dim3(SEQ/64, NUM_HEADS/2, 2), 256, 0, stream>>>(
      QKVb, Kswz, Vswz, xb, QKV_DIM);
  cvt_bf16<<<nwq/2048, 256, 0, stream>>>(Wo, Wb, nwq, 1.0f);
  gemm_bt<true><<<dim3(D_MODEL/128, MTOT/128), 256, 0, stream>>>(xb, Wb, (void*)out, MTOT, D_MODEL, D_MODEL);
}

// Round 13
// 326.310 us; speedup vs baseline: 1.1723x; 1.1723x over previous
//
#include <hip/hip_runtime.h>
#include <stdint.h>

// R19: full revert of R18 (attn head-pairing: VGPR 96 -> occupancy 12.7%,
// 124us; BK=64 gemm: non-attn 258us -- both regressions). Base = R17
// (341.4us: attn 96.6, VGPR 60, bank-conflicts 0). Two SAFE additive edits:
//  1. Launch consolidation: 5 cvt launches -> 1 region-dispatched kernel;
//     Wo converts early into its own ws slot (ws_size-guarded, fallback to
//     old path) so attn->gemm2 has no cvt serialization point. 9->5 launches.
//  2. Bijective XCD swizzle (m204) on both gemms' block ids (1-D grid).
// No sync-structure changes (R9/R13/R18: structure gambles regress).

typedef unsigned short u16;
typedef short bf16x8 __attribute__((ext_vector_type(8)));
typedef float f32x4 __attribute__((ext_vector_type(4)));

#define D_MODEL 2048
#define QKV_DIM 3072
#define NUM_HEADS 32
#define HEAD_DIM 64
#define SEQ 2048
#define MTOT 4096

static __device__ __forceinline__ u16 f2bf(float f){
  uint32_t u = __builtin_bit_cast(uint32_t, f);
  u += 0x7FFFu + ((u >> 16) & 1u);
  return (u16)(u >> 16);
}

static __device__ __forceinline__ float exp2_fast(float x){
  float r;
  asm("v_exp_f32 %0, %1" : "=v"(r) : "v"(x));
  return r;
}

static __device__ __forceinline__ uint32_t cvt_pk_bf16(float lo, float hi){
  uint32_t r;
  asm("v_cvt_pk_bf16_f32 %0, %1, %2" : "=v"(r) : "v"(lo), "v"(hi));
  return r;
}

static __device__ __forceinline__ void gload16(const u16* g, u16* l){
  __builtin_amdgcn_global_load_lds(
      (__attribute__((address_space(1))) uint32_t*)(uintptr_t)g,
      (__attribute__((address_space(3))) uint32_t*)l,
      16, 0, 0);
}

static __device__ __forceinline__ void cvt8(const float* __restrict__ src,
                                            u16* __restrict__ dst,
                                            int i, float scl){
  float4 a = *(const float4*)(src + i);
  float4 b = *(const float4*)(src + i + 4);
  union { u16 h[8]; uint4 v; } t;
  t.h[0]=f2bf(a.x*scl); t.h[1]=f2bf(a.y*scl); t.h[2]=f2bf(a.z*scl); t.h[3]=f2bf(a.w*scl);
  t.h[4]=f2bf(b.x*scl); t.h[5]=f2bf(b.y*scl); t.h[6]=f2bf(b.z*scl); t.h[7]=f2bf(b.w*scl);
  *(uint4*)(dst + i) = t.v;
}

__global__ __launch_bounds__(256)
void cvt_bf16(const float* __restrict__ in, u16* __restrict__ out, int n,
              float scl){
  const int i = (blockIdx.x * 256 + threadIdx.x) * 8;
  if (i >= n) return;
  cvt8(in, out, i, scl);
}

// Fused conversion of all inputs: block-range dispatch (uniform branch).
// blocks: x:[0,4096) Wq:[4096,6144) Wk:[6144,6656) Wv:[6656,7168) Wo:[7168,9216)
__global__ __launch_bounds__(256)
void cvt_all(const float* __restrict__ x,  const float* __restrict__ Wq,
             const float* __restrict__ Wk, const float* __restrict__ Wv,
             const float* __restrict__ Wo,
             u16* __restrict__ xb, u16* __restrict__ Wb,
             u16* __restrict__ Wob, float qscl){
  const int bid = blockIdx.x;
  const float* src; u16* dst; int off; float scl = 1.0f;
  if (bid < 4096){        src = x;  dst = xb;                              off = bid;        }
  else if (bid < 6144){   src = Wq; dst = Wb;                              off = bid - 4096; scl = qscl; }
  else if (bid < 6656){   src = Wk; dst = Wb + (size_t)D_MODEL*D_MODEL;    off = bid - 6144; }
  else if (bid < 7168){   src = Wv; dst = Wb + (size_t)2560*D_MODEL;       off = bid - 6656; }
  else {                  src = Wo; dst = Wob;                             off = bid - 7168; }
  const int i = (off * 256 + threadIdx.x) * 8;
  cvt8(src, dst, i, scl);
}

// C[M,N] = A[M,K] @ B[N,K]^T. m97 structure (BK=32, reverted), 1-D grid with
// bijective XCD swizzle (m204): contiguous swz chunks per XCD -> L2 locality.
template <bool F32OUT>
__global__ __launch_bounds__(256)
void gemm_bt(const u16* __restrict__ A, const u16* __restrict__ B,
             void* __restrict__ Cv, int M, int N, int K, int nbx){
  constexpr int BK = 32;
  __shared__ __attribute__((aligned(16))) u16 As[128*BK];
  __shared__ __attribute__((aligned(16))) u16 Bs[128*BK];
  const int tid  = threadIdx.x;
  const int wave = tid >> 6, lane = tid & 63;
  const int quad = lane >> 4, l16 = lane & 15;
  const int wrow = wave >> 1, wcol = wave & 1;
  // bijective XCD swizzle
  const int nwg = gridDim.x;
  const int qq = nwg >> 3, rr = nwg & 7;
  const int xcd = blockIdx.x & 7, lin = blockIdx.x >> 3;
  const int swz = (xcd < rr ? xcd*(qq+1) : rr*(qq+1) + (xcd-rr)*qq) + lin;
  const int m0 = (swz / nbx) * 128, n0 = (swz % nbx) * 128;
  const int srow = lane >> 2, scol = (lane & 3) * 8;

  const f32x4 zero = {0.f, 0.f, 0.f, 0.f};
  f32x4 acc[4][4];
#pragma unroll
  for (int i = 0; i < 4; i++)
#pragma unroll
    for (int j = 0; j < 4; j++) acc[i][j] = zero;

  for (int k0 = 0; k0 < K; k0 += BK){
#pragma unroll
    for (int t = 0; t < 2; t++){
      const int chunk = wave + t*4;
      gload16(A + (size_t)(m0 + chunk*16 + srow)*K + k0 + scol, As + chunk*16*BK);
      gload16(B + (size_t)(n0 + chunk*16 + srow)*K + k0 + scol, Bs + chunk*16*BK);
    }
    __syncthreads();
    bf16x8 af[4], bfr[4];
#pragma unroll
    for (int mi = 0; mi < 4; mi++)
      af[mi] = *(const bf16x8*)(As + (wrow*64 + mi*16 + l16)*BK + quad*8);
#pragma unroll
    for (int ni = 0; ni < 4; ni++)
      bfr[ni] = *(const bf16x8*)(Bs + (wcol*64 + ni*16 + l16)*BK + quad*8);
#pragma unroll
    for (int mi = 0; mi < 4; mi++)
#pragma unroll
      for (int ni = 0; ni < 4; ni++)
        acc[mi][ni] = __builtin_amdgcn_mfma_f32_16x16x32_bf16(af[mi], bfr[ni], acc[mi][ni], 0, 0, 0);
    __syncthreads();
  }
#pragma unroll
  for (int mi = 0; mi < 4; mi++)
#pragma unroll
    for (int ni = 0; ni < 4; ni++){
      const int col = n0 + wcol*64 + ni*16 + l16;
#pragma unroll
      for (int r = 0; r < 4; r++){
        const int row = m0 + wrow*64 + mi*16 + quad*4 + r;
        if constexpr (F32OUT)
          ((float*)Cv)[(size_t)row*N + col] = acc[mi][ni][r];
        else
          ((u16*)Cv)[(size_t)row*N + col] = f2bf(acc[mi][ni][r]);
      }
    }
}

// kvtrans: build per-(b,hk,j) 8KB K and V tiles in the exact (swizzled) LDS
// image attn wants. K[row=key][chunk c] stored at row*64 + (c^(row&7))*8.
// V transposed (rows=d) with the PV k-permutation, same XOR swizzle.
__global__ __launch_bounds__(256)
void kvtrans(const u16* __restrict__ QKV, u16* __restrict__ Ksw,
             u16* __restrict__ Vsw){
  __shared__ u16 Ls[64*72];
  const int tid = threadIdx.x;
  const int st = blockIdx.x, hk = blockIdx.y, b = blockIdx.z;
  const size_t rb = (size_t)b * SEQ;
  const size_t tbase = ((size_t)(b*8 + hk)*32 + st) * 4096;

#pragma unroll
  for (int t = 0; t < 2; t++){
    const int task = t*256 + tid;
    const int r = task >> 3, c = task & 7;
    uint4 kv = *(const uint4*)(QKV + (rb + st*64 + r)*QKV_DIM + 2048 + hk*HEAD_DIM + c*8);
    *(uint4*)(Ksw + tbase + r*64 + (size_t)((c ^ (r & 7)) * 8)) = kv;
  }
#pragma unroll
  for (int t = 0; t < 2; t++){
    const int task = t*256 + tid;
    const int r = task >> 3, c = task & 7;
    *(uint4*)(Ls + r*72 + c*8) =
        *(const uint4*)(QKV + (rb + st*64 + r)*QKV_DIM + 2560 + hk*HEAD_DIM + c*8);
  }
  __syncthreads();
#pragma unroll
  for (int t = 0; t < 2; t++){
    const int task = t*256 + tid;
    const int d = task >> 3, sc = task & 7;
    union { u16 h[8]; uint4 v; } tmp;
#pragma unroll
    for (int e = 0; e < 8; e++){
      const int key = ((2*(sc>>2) + (e>>2))<<4) + ((sc&3)<<2) + (e&3);
      tmp.h[e] = Ls[key*72 + d];
    }
    *(uint4*)(Vsw + tbase + d*64 + (size_t)((sc ^ (d & 7)) * 8)) = tmp.v;
  }
}

// attn (R17 verbatim): swapped QK^T, in-register P, log2 softmax + defer-max,
// complement-balanced qt, double-buffered gload_lds staging, XOR reads.
__global__ __launch_bounds__(256)
void attn(const u16* __restrict__ Q, const u16* __restrict__ Ksw,
          const u16* __restrict__ Vsw, u16* __restrict__ O, int qs){
  __shared__ __attribute__((aligned(16))) u16 Ks[2][64*64];
  __shared__ __attribute__((aligned(16))) u16 Vt[2][64*64];
  const int tid = threadIdx.x;
  const int wave = tid >> 6, lane = tid & 63, quad = lane >> 4, l16 = lane & 15;
  const int g_ = (blockIdx.x + blockIdx.y) & 31;
  const int qt = blockIdx.z ? (31 - g_) : g_;
  const int h = blockIdx.y, b = blockIdx.z;
  const int hk = h >> 2;
  const size_t rb = (size_t)b * SEQ;
  const size_t hb = ((size_t)(b*8 + hk)) * 32;

  const int qrow = wave*16 + l16;
  const int sw = l16 & 7;

  bf16x8 qf[2];
  {
    const u16* qp = Q + (rb + qt*64 + wave*16 + l16)*qs + h*HEAD_DIM;
    qf[0] = *(const bf16x8*)(qp + quad*8);
    qf[1] = *(const bf16x8*)(qp + 32 + quad*8);
  }
  const f32x4 zero = {0.f, 0.f, 0.f, 0.f};
  f32x4 oacc[4];
#pragma unroll
  for (int i = 0; i < 4; i++) oacc[i] = zero;
  float m_i = -INFINITY;
  float l_i = 0.f;

  {
    const u16* kt = Ksw + hb * 4096;
    const u16* vt = Vsw + hb * 4096;
#pragma unroll
    for (int t = 0; t < 2; t++){
      const int ch = wave*2 + t;
      gload16(kt + ch*512 + lane*8, &Ks[0][ch*512]);
      gload16(vt + ch*512 + lane*8, &Vt[0][ch*512]);
    }
  }
  int cur = 0;

  for (int j = 0; j <= qt; ++j){
    __syncthreads();
    if (j < qt){
      const u16* kt = Ksw + (hb + j + 1) * 4096;
      const u16* vt = Vsw + (hb + j + 1) * 4096;
#pragma unroll
      for (int t = 0; t < 2; t++){
        const int ch = wave*2 + t;
        gload16(kt + ch*512 + lane*8, &Ks[cur^1][ch*512]);
        gload16(vt + ch*512 + lane*8, &Vt[cur^1][ch*512]);
      }
    }
    const u16* Ksb = Ks[cur];
    const u16* Vtb = Vt[cur];

    f32x4 st[4];
#pragma unroll
    for (int ni = 0; ni < 4; ni++){
      f32x4 s = zero;
#pragma unroll
      for (int ss = 0; ss < 2; ss++){
        bf16x8 kf = *(const bf16x8*)(Ksb + ((ni*16 + l16) << 6) +
                                     (((ss*4 + quad) ^ sw) << 3));
        s = __builtin_amdgcn_mfma_f32_16x16x32_bf16(kf, qf[ss], s, 0, 0, 0);
      }
      st[ni] = s;
    }
    if (j == qt){
#pragma unroll
      for (int ni = 0; ni < 4; ni++)
#pragma unroll
        for (int r = 0; r < 4; r++)
          if (ni*16 + quad*4 + r > qrow) st[ni][r] = -INFINITY;
    }

    float mx = fmaxf(fmaxf(fmaxf(st[0][0], st[0][1]), fmaxf(st[0][2], st[0][3])),
                     fmaxf(fmaxf(st[1][0], st[1][1]), fmaxf(st[1][2], st[1][3])));
    mx = fmaxf(mx, fmaxf(fmaxf(fmaxf(st[2][0], st[2][1]), fmaxf(st[2][2], st[2][3])),
                         fmaxf(fmaxf(st[3][0], st[3][1]), fmaxf(st[3][2], st[3][3]))));
    mx = fmaxf(mx, __shfl_xor(mx, 16));
    mx = fmaxf(mx, __shfl_xor(mx, 32));

    if (__all(mx <= m_i + 10.f)){
      float ps = 0.f;
#pragma unroll
      for (int ni = 0; ni < 4; ni++)
#pragma unroll
        for (int r = 0; r < 4; r++){
          const float p = exp2_fast(st[ni][r] - m_i);
          st[ni][r] = p;
          ps += p;
        }
      ps += __shfl_xor(ps, 16);
      ps += __shfl_xor(ps, 32);
      l_i += ps;
    } else {
      const float mn = fmaxf(m_i, mx);
      const float alpha = exp2_fast(m_i - mn);
      float ps = 0.f;
#pragma unroll
      for (int ni = 0; ni < 4; ni++)
#pragma unroll
        for (int r = 0; r < 4; r++){
          const float p = exp2_fast(st[ni][r] - mn);
          st[ni][r] = p;
          ps += p;
        }
      ps += __shfl_xor(ps, 16);
      ps += __shfl_xor(ps, 32);
      l_i = l_i*alpha + ps;
      m_i = mn;
      float ar[4];
#pragma unroll
      for (int r = 0; r < 4; r++) ar[r] = __shfl(alpha, quad*4 + r);
#pragma unroll
      for (int ci = 0; ci < 4; ci++)
#pragma unroll
        for (int r = 0; r < 4; r++) oacc[ci][r] *= ar[r];
    }

    bf16x8 pfr[2];
#pragma unroll
    for (int ss = 0; ss < 2; ss++){
      union { uint32_t w[4]; bf16x8 v; } pk;
      pk.w[0] = cvt_pk_bf16(st[2*ss][0],   st[2*ss][1]);
      pk.w[1] = cvt_pk_bf16(st[2*ss][2],   st[2*ss][3]);
      pk.w[2] = cvt_pk_bf16(st[2*ss+1][0], st[2*ss+1][1]);
      pk.w[3] = cvt_pk_bf16(st[2*ss+1][2], st[2*ss+1][3]);
      pfr[ss] = pk.v;
    }

#pragma unroll
    for (int ss = 0; ss < 2; ss++)
#pragma unroll
      for (int ci = 0; ci < 4; ci++){
        bf16x8 vf = *(const bf16x8*)(Vtb + ((ci*16 + l16) << 6) +
                                     (((ss*4 + quad) ^ sw) << 3));
        oacc[ci] = __builtin_amdgcn_mfma_f32_16x16x32_bf16(pfr[ss], vf, oacc[ci], 0, 0, 0);
      }
    cur ^= 1;
  }

  float lf[4];
#pragma unroll
  for (int r = 0; r < 4; r++) lf[r] = __shfl(l_i, quad*4 + r);
#pragma unroll
  for (int ci = 0; ci < 4; ci++)
#pragma unroll
    for (int r = 0; r < 4; r++){
      const size_t row = rb + qt*64 + wave*16 + quad*4 + r;
      O[row*D_MODEL + h*HEAD_DIM + ci*16 + l16] = f2bf(oacc[ci][r] / lf[r]);
    }
}

extern "C" void kernel_launch(void* const* d_in, const int* in_sizes, int n_in,
                              void* d_out, int out_size, void* d_ws, size_t ws_size,
                              hipStream_t stream){
  const float* x  = (const float*)d_in[0];
  const float* Wq = (const float*)d_in[1];
  const float* Wk = (const float*)d_in[2];
  const float* Wv = (const float*)d_in[3];
  const float* Wo = (const float*)d_in[4];
  float* out = (float*)d_out;

  u16* xb   = (u16*)d_ws;                    // x / later attn-out  [4096,2048]
  u16* Wb   = xb + (size_t)MTOT*D_MODEL;     // fused weights [3072,2048]
  u16* Wob  = Wb + (size_t)QKV_DIM*D_MODEL;  // Wo bf16 [2048,2048] (if ws fits)
  u16* QKVb = (u16*)d_out;                   // QKV scratch [4096,3072] bf16
  u16* Kswz = Wb;                            // swizzled K tiles (Wq region, dead after gemm1)
  u16* Vswz = Wb + (size_t)2*1024*1024;      // swizzled V tiles

  const int nwq = D_MODEL*D_MODEL;
  const float QSCL = 0.125f * 1.44269504f;   // softmax scale * log2(e)

  const size_t ws_need = ((size_t)MTOT*D_MODEL + (size_t)QKV_DIM*D_MODEL +
                          (size_t)D_MODEL*D_MODEL) * sizeof(u16);
  const bool wob_fits = (ws_size >= ws_need);

  if (wob_fits){
    cvt_all<<<9216, 256, 0, stream>>>(x, Wq, Wk, Wv, Wo, xb, Wb, Wob, QSCL);
  } else {
    cvt_all<<<7168, 256, 0, stream>>>(x, Wq, Wk, Wv, Wo, xb, Wb, Wob, QSCL);
  }
  gemm_bt<false><<<(QKV_DIM/128)*(MTOT/128), 256, 0, stream>>>(
      xb, Wb, QKVb, MTOT, QKV_DIM, D_MODEL, QKV_DIM/128);
  kvtrans<<<dim3(SEQ/64, 8, 2), 256, 0, stream>>>(QKVb, Kswz, Vswz);
  attn<<<dim3(SEQ/64, NUM_HEADS, 2), 256, 0, stream>>>(
      QKVb, Kswz, Vswz, xb, QKV_DIM);
  const u16* Bw2;
  if (wob_fits){
    Bw2 = Wob;
  } else {
    cvt_bf16<<<nwq/2048, 256, 0, stream>>>(Wo, Wb, nwq, 1.0f);
    Bw2 = Wb;
  }
  gemm_bt<true><<<(D_MODEL/128)*(MTOT/128), 256, 0, stream>>>(
      xb, Bw2, (void*)out, MTOT, D_MODEL, D_MODEL, D_MODEL/128);
}